// Round 1
// baseline (29877.499 us; speedup 1.0000x reference)
//
#include <hip/hip_runtime.h>
#include <hip/hip_cooperative_groups.h>
#include <math.h>

namespace cg = cooperative_groups;
typedef unsigned long long ull;
typedef unsigned int u32;

#define NB 32        // batch
#define SEQ 128      // encoder sequence length
#define HD 1024      // hidden
#define NV 32000     // vocab out
#define TD 64        // decode steps
#define SOS_TOK 1

// d_out layout (floats): toks [32][64] | h [1][32][1024] | logits [32][64][32000]
#define TOKS_OFF 0
#define HOUT_OFF 2048
#define LOG_OFF  34816

__device__ __forceinline__ float dot4(float4 a, float4 b){
  return a.x*b.x + a.y*b.y + a.z*b.z + a.w*b.w;
}
__device__ __forceinline__ float sigf(float x){ return 1.0f/(1.0f+expf(-x)); }
// monotone sortable key: high 32 = order-preserving float bits, low 32 = ~col
// (ties: larger ~col = smaller col wins, matching np.argmax first-index rule)
__device__ __forceinline__ ull fkey(float v, u32 col){
  u32 kb = __float_as_uint(v);
  kb = (kb & 0x80000000u) ? ~kb : (kb | 0x80000000u);
  return ((ull)kb << 32) | (u32)(~col);
}

// ---------------- prep: decode tokens (int32 or int64), init h0, init step-best cells
__global__ void k_prep(const int* __restrict__ raw, const float* __restrict__ hidden,
                       float* __restrict__ h0, int* __restrict__ toks, ull* __restrict__ SB){
  const int tid = threadIdx.x, blk = blockIdx.x;
  if (blk == 0){
    __shared__ int allz;
    if (tid == 0) allz = 1;
    __syncthreads();
    bool bad = false;
    // if input is int64, every odd 32-bit word (hi word) is 0; reads stay within 4096 i32 = min buffer
    for (int i = tid; i < (NB*SEQ)/2; i += 256) if (raw[2*i+1] != 0) bad = true;
    if (bad) allz = 0;   // benign race: all writers store 0
    __syncthreads();
    const int is64 = allz;
    for (int i = tid; i < NB*SEQ; i += 256) toks[i] = is64 ? raw[2*i] : raw[i];
  } else if (blk <= 32){
    const int b = blk - 1;
    for (int k = tid; k < HD; k += 256) h0[b*HD + k] = hidden[b*HD + k];
  } else if (blk == 33){
    if (tid < NB){
      SB[tid] = 0ull;                                             // parity-0 cell: target of decode step 0's logits argmax
      SB[NB + tid] = (0xFFFFFFFFull << 32) | (u32)(~(u32)SOS_TOK); // parity-1 cell: read by decode step 0 -> SOS
    }
  }
}

// ---------------- encoder scan: 128 sequential GRU steps, cooperative, 1 grid.sync/step
// grid 256 x 512. block: bh=blk&1 (batch half), jjg=blk>>1 (column group of 8).
// wave = one hidden column jj (1024 waves x 2 batch-halves = 2048 wave-tasks).
// lane: b16=lane&15 (batch within half), q=lane>>4 (K quarter of 256).
__global__ void __launch_bounds__(512, 4)
k_enc(const int* __restrict__ toks, const float* __restrict__ emb,
      const float* __restrict__ Wih, const float* __restrict__ Whh,
      const float* __restrict__ bih, const float* __restrict__ bhh,
      float* __restrict__ h0, float* __restrict__ h1){
  cg::grid_group grid = cg::this_grid();
  const int tid = threadIdx.x;
  const int wid = tid >> 6, lane = tid & 63;
  const int b16 = lane & 15, q = lane >> 4;
  const int bh = blockIdx.x & 1, jjg = blockIdx.x >> 1;
  const int b  = bh*16 + b16;
  const int jj = jjg*8 + wid;
  const int k0 = q*256;
  const float4* wiR = (const float4*)(Wih + (size_t)jj*HD + k0);
  const float4* whR = (const float4*)(Whh + (size_t)jj*HD + k0);
  // rows jj / jj+1024 / jj+2048 are the r / z / n gate rows; +1024 rows = +262144 float4
  const float bR  = bih[jj] + bhh[jj];
  const float bZ  = bih[jj+1024] + bhh[jj+1024];
  const float bNX = bih[jj+2048];
  const float bNH = bhh[jj+2048];
  for (int s = 0; s < SEQ; s++){
    const float* hcur = (s & 1) ? h1 : h0;
    float*       hnxt = (s & 1) ? h0 : h1;
    const int tok = toks[b*SEQ + s];
    const float4* xr = (const float4*)(emb + (size_t)tok*HD + k0);
    const float4* hr = (const float4*)(hcur + (size_t)b*HD + k0);
    float aR = 0.f, aZ = 0.f, aNX = 0.f, aNH = 0.f;
    #pragma unroll 4
    for (int i = 0; i < 64; i++){
      const float4 xv = xr[i], hv = hr[i];
      aR  += dot4(xv, wiR[i]);
      aZ  += dot4(xv, wiR[i + 262144]);
      aNX += dot4(xv, wiR[i + 524288]);
      aR  += dot4(hv, whR[i]);
      aZ  += dot4(hv, whR[i + 262144]);
      aNH += dot4(hv, whR[i + 524288]);
    }
    aR  += __shfl_xor(aR,16);  aR  += __shfl_xor(aR,32);
    aZ  += __shfl_xor(aZ,16);  aZ  += __shfl_xor(aZ,32);
    aNX += __shfl_xor(aNX,16); aNX += __shfl_xor(aNX,32);
    aNH += __shfl_xor(aNH,16); aNH += __shfl_xor(aNH,32);
    const float r  = sigf(aR + bR);
    const float z  = sigf(aZ + bZ);
    const float n  = tanhf(aNX + bNX + r*(aNH + bNH));
    const float h2 = (1.f - z)*n + z*hcur[(size_t)b*HD + jj];
    if (q == 0) hnxt[(size_t)b*HD + jj] = h2;
    grid.sync();
  }
}

// ---------------- decoder: 64 steps, cooperative, 2 grid.sync/step
// phase A: GRU (reads prev-step argmax from SB, gathers embedding rows directly)
// phase B: fp32 logits on 250 blocks (128 cols each), write d_out, per-row best -> atomicMax(SB)
__global__ void __launch_bounds__(512, 4)
k_dec(const float* __restrict__ emb, const float* __restrict__ Wih, const float* __restrict__ Whh,
      const float* __restrict__ bih, const float* __restrict__ bhh,
      const float* __restrict__ outW, const float* __restrict__ outB,
      float* __restrict__ h0, float* __restrict__ h1,
      ull* __restrict__ SB, float* __restrict__ dout){
  cg::grid_group grid = cg::this_grid();
  __shared__ float ltile[128][33];   // transpose staging for coalesced logits writes
  __shared__ ull   wbest[8][NB];
  const int tid = threadIdx.x;
  const int wid = tid >> 6, lane = tid & 63;
  // phase-A mapping (same as encoder)
  const int b16 = lane & 15, q = lane >> 4;
  const int bh = blockIdx.x & 1, jjg = blockIdx.x >> 1;
  const int bA = bh*16 + b16;
  const int jj = jjg*8 + wid;
  const int k0 = q*256;
  // phase-B mapping
  const int bB = lane & 31, kh = lane >> 5;
  const float4* wiR = (const float4*)(Wih + (size_t)jj*HD + k0);
  const float4* whR = (const float4*)(Whh + (size_t)jj*HD + k0);
  const float bR  = bih[jj] + bhh[jj];
  const float bZ  = bih[jj+1024] + bhh[jj+1024];
  const float bNX = bih[jj+2048];
  const float bNH = bhh[jj+2048];

  for (int t = 0; t < TD; t++){
    const float* hcur = (t & 1) ? h1 : h0;
    float*       hnxt = (t & 1) ? h0 : h1;
    const ull* SBp = SB + (size_t)((t+1)&1)*NB;   // written by step t-1's phase B (or prep: SOS)
    // ---------- phase A: GRU cell ----------
    {
      const int tok = (int)(~(u32)SBp[bA]);
      const float4* xr = (const float4*)(emb + (size_t)tok*HD + k0);
      const float4* hr = (const float4*)(hcur + (size_t)bA*HD + k0);
      float aR = 0.f, aZ = 0.f, aNX = 0.f, aNH = 0.f;
      #pragma unroll 4
      for (int i = 0; i < 64; i++){
        const float4 xv = xr[i], hv = hr[i];
        aR  += dot4(xv, wiR[i]);
        aZ  += dot4(xv, wiR[i + 262144]);
        aNX += dot4(xv, wiR[i + 524288]);
        aR  += dot4(hv, whR[i]);
        aZ  += dot4(hv, whR[i + 262144]);
        aNH += dot4(hv, whR[i + 524288]);
      }
      aR  += __shfl_xor(aR,16);  aR  += __shfl_xor(aR,32);
      aZ  += __shfl_xor(aZ,16);  aZ  += __shfl_xor(aZ,32);
      aNX += __shfl_xor(aNX,16); aNX += __shfl_xor(aNX,32);
      aNH += __shfl_xor(aNH,16); aNH += __shfl_xor(aNH,32);
      const float r  = sigf(aR + bR);
      const float z  = sigf(aZ + bZ);
      const float n  = tanhf(aNX + bNX + r*(aNH + bNH));
      const float h2 = (1.f - z)*n + z*hcur[(size_t)bA*HD + jj];
      if (q == 0){
        hnxt[(size_t)bA*HD + jj] = h2;
        if (t == TD-1) dout[HOUT_OFF + (size_t)bA*HD + jj] = h2;  // final hidden output
      }
      if (blockIdx.x == 0 && t > 0 && tid < NB)
        dout[TOKS_OFF + tid*TD + (t-1)] = (float)(int)(~(u32)SBp[tid]);
    }
    grid.sync();
    // ---------- phase B: logits + argmax candidates ----------
    if (blockIdx.x < 250){
      const float4* hr2 = (const float4*)(hnxt + (size_t)bB*HD + kh*512);
      const int colbase = blockIdx.x*128 + wid*16;
      const float* wb = outW + (size_t)colbase*HD + kh*512;
      float acc[16];
      #pragma unroll
      for (int c = 0; c < 16; c++) acc[c] = 0.f;
      #pragma unroll 2
      for (int i = 0; i < 128; i++){
        const float4 hv = hr2[i];
        #pragma unroll
        for (int c = 0; c < 16; c++){
          const float4 wv = ((const float4*)(wb + (size_t)c*HD))[i];
          acc[c] += dot4(hv, wv);
        }
      }
      float bestv = -3.4e38f; int bestc = 0;
      #pragma unroll
      for (int c = 0; c < 16; c++){
        float v = acc[c] + __shfl_xor(acc[c], 32);  // combine the two K halves
        v += outB[colbase + c];
        acc[c] = v;
        if (v > bestv){ bestv = v; bestc = c; }     // ascending c + strict > : first-index tie rule
      }
      if (kh == 0){
        #pragma unroll
        for (int c = 0; c < 16; c++) ltile[wid*16 + c][bB] = acc[c];
        wbest[wid][bB] = fkey(bestv, (u32)(colbase + bestc));
      }
      __syncthreads();
      {
        const int bb = tid >> 4, cs = (tid & 15)*8;
        float* orow = dout + LOG_OFF + (size_t)bb*((size_t)TD*NV) + (size_t)t*NV
                      + (size_t)blockIdx.x*128 + cs;
        #pragma unroll
        for (int a = 0; a < 2; a++){
          float4 v;
          v.x = ltile[cs+4*a+0][bb]; v.y = ltile[cs+4*a+1][bb];
          v.z = ltile[cs+4*a+2][bb]; v.w = ltile[cs+4*a+3][bb];
          ((float4*)orow)[a] = v;
        }
      }
      if (tid < NB){
        ull m = wbest[0][tid];
        #pragma unroll
        for (int w2 = 1; w2 < 8; w2++){ ull x = wbest[w2][tid]; m = x > m ? x : m; }
        atomicMax(&SB[(size_t)(t&1)*NB + tid], m);
      }
    } else if (blockIdx.x == 255){
      // recycle the cell set phase A just consumed; it is the target of step t+1's atomics
      if (tid < NB) SB[(size_t)((t+1)&1)*NB + tid] = 0ull;
    }
    grid.sync();
  }
  // argmax of the last step
  if (blockIdx.x == 0 && tid < NB)
    dout[TOKS_OFF + tid*TD + (TD-1)] = (float)(int)(~(u32)SB[(size_t)((TD-1)&1)*NB + tid]);
}

extern "C" void kernel_launch(void* const* d_in, const int* in_sizes, int n_in,
                              void* d_out, int out_size, void* d_ws, size_t ws_size,
                              hipStream_t stream){
  (void)in_sizes; (void)n_in; (void)out_size; (void)ws_size;
  const int*   input   = (const int*)d_in[0];
  const float* hidden  = (const float*)d_in[1];
  // d_in[2] = max_output_length (fixed 64, ignored)
  const float* enc_emb = (const float*)d_in[3];
  const float* enc_Wih = (const float*)d_in[4];
  const float* enc_Whh = (const float*)d_in[5];
  const float* enc_bih = (const float*)d_in[6];
  const float* enc_bhh = (const float*)d_in[7];
  const float* dec_emb = (const float*)d_in[8];
  const float* dec_Wih = (const float*)d_in[9];
  const float* dec_Whh = (const float*)d_in[10];
  const float* dec_bih = (const float*)d_in[11];
  const float* dec_bhh = (const float*)d_in[12];
  const float* outW    = (const float*)d_in[13];
  const float* outB    = (const float*)d_in[14];
  float* dout = (float*)d_out;

  char* w = (char*)d_ws;
  int*   toks = (int*)w;                               // 16 KB
  float* h0   = (float*)(w + (16<<10));                // 128 KB
  float* h1   = (float*)(w + (16<<10) + (128<<10));    // 128 KB
  ull*   SB   = (ull*)(w + (16<<10) + (256<<10));      // 2 x 32 packed best cells

  k_prep<<<dim3(64), dim3(256), 0, stream>>>(input, hidden, h0, toks, SB);

  {
    void* args[] = { (void*)&toks, (void*)&enc_emb, (void*)&enc_Wih, (void*)&enc_Whh,
                     (void*)&enc_bih, (void*)&enc_bhh, (void*)&h0, (void*)&h1 };
    hipLaunchCooperativeKernel((void*)k_enc, dim3(256), dim3(512), args, 0, stream);
  }
  {
    void* args[] = { (void*)&dec_emb, (void*)&dec_Wih, (void*)&dec_Whh, (void*)&dec_bih,
                     (void*)&dec_bhh, (void*)&outW, (void*)&outB, (void*)&h0, (void*)&h1,
                     (void*)&SB, (void*)&dout };
    hipLaunchCooperativeKernel((void*)k_dec, dim3(256), dim3(512), args, 0, stream);
  }
}